// Round 1
// baseline (324.546 us; speedup 1.0000x reference)
//
#include <hip/hip_runtime.h>
#include <cstdint>

// Problem constants (from the reference)
#define LL    200
#define QQ    21
#define MM    1024
#define START 133        // 2*L//3
#define NS    67         // L - START
#define RGH   0.01f
#define RGJ   0.01f

// kern_logz tiling
#define TJ    32         // j-tile staged in LDS
#define APAD  24         // padded a-stride (24 floats = 96 B, 16B-aligned rows)

// ws layout: acc[0]=sum(J^2), acc[1]=sum(J*fij masked), acc[2]=sum_n,i w[n]*logZ[n,i]
// tokT (transposed tokens, [j][n]) at byte offset 256.

__device__ __forceinline__ float block_reduce_sum(float v) {
  // blockDim.x == 256 (4 waves) assumed
  __shared__ float sm[4];
  #pragma unroll
  for (int off = 32; off > 0; off >>= 1) v += __shfl_down(v, off, 64);
  const int lane = threadIdx.x & 63;
  const int wv   = threadIdx.x >> 6;
  __syncthreads();               // protect sm across repeated calls
  if (lane == 0) sm[wv] = v;
  __syncthreads();
  float r = 0.0f;
  if (threadIdx.x == 0) r = sm[0] + sm[1] + sm[2] + sm[3];
  return r;                      // valid in thread 0 only
}

// ---------------------------------------------------------------------------
// Kernel A: sum(J^2) over all of J, and sum(J*fij) over {i>=START, j<i}.
// Grid (LL, 4) x 256 threads; coalesced grid-stride within each i-slice.
// ---------------------------------------------------------------------------
__global__ __launch_bounds__(256) void kern_jsum(
    const float* __restrict__ J, const float* __restrict__ fij,
    float* __restrict__ acc) {
  const int i = blockIdx.x;
  const size_t base = (size_t)i * (QQ * LL * QQ);
  const int total = QQ * LL * QQ;      // 88200 per i-slice
  float j2 = 0.0f, e = 0.0f;
  for (int idx = blockIdx.y * 256 + threadIdx.x; idx < total;
       idx += 256 * gridDim.y) {
    const float v = J[base + idx];
    j2 += v * v;
    if (i >= START) {
      const int j = (idx % (LL * QQ)) / QQ;   // constant-div -> magic mul
      if (j < i) e += v * fij[base + idx];
    }
  }
  const float tj2 = block_reduce_sum(j2);
  const float te  = block_reduce_sum(e);
  if (threadIdx.x == 0) {
    atomicAdd(acc + 0, tj2);
    if (i >= START) atomicAdd(acc + 1, te);
  }
}

// ---------------------------------------------------------------------------
// Token transpose: tokT[j][n] = X[n][j]  (coalesced writes)
// ---------------------------------------------------------------------------
__global__ __launch_bounds__(256) void kern_tokT(
    const int* __restrict__ X, int* __restrict__ tokT) {
  const int idx = blockIdx.x * 256 + threadIdx.x;
  if (idx < LL * MM) {
    const int j = idx / MM;
    const int n = idx - j * MM;
    tokT[idx] = X[n * LL + j];
  }
}

// ---------------------------------------------------------------------------
// Kernel B: per (i, n) compute logits[a] = h[i,a] + sum_{j<i} J[i,a,j,tok[n,j]],
// then logZ = logsumexp_a, accumulate sum w[n]*logZ.
// Grid (NS, MM/256) x 256 threads. One block: one site i, 256 sequences.
// J[i,:,j-tile,:] is staged in LDS re-laid-out as [j][b][a] (APAD-padded rows)
// so each (n,j) reads one contiguous 21-float (16B-aligned) row.
// ---------------------------------------------------------------------------
__global__ __launch_bounds__(256) void kern_logz(
    const float* __restrict__ J, const int* __restrict__ Xtok,
    const int* __restrict__ tokT, const int useT,
    const float* __restrict__ h, const float* __restrict__ w,
    float* __restrict__ acc) {
  __shared__ __align__(16) float ldsJ[TJ * QQ * APAD];  // 64512 B
  const int i = START + blockIdx.x;
  const int t = threadIdx.x;
  const int n = blockIdx.y * 256 + t;

  float lg[QQ];
  #pragma unroll
  for (int a = 0; a < QQ; ++a) lg[a] = 0.0f;

  const float* Ji = J + (size_t)i * (QQ * LL * QQ);

  for (int j0 = 0; j0 < i; j0 += TJ) {
    const int tj = min(TJ, i - j0);
    const int cnt = tj * QQ;
    __syncthreads();
    // Stage: for each a, the (j,b) plane is contiguous in global memory.
    for (int a = 0; a < QQ; ++a) {
      const float* src = Ji + a * (LL * QQ) + j0 * QQ;
      for (int idx = t; idx < cnt; idx += 256) {
        const int jl = idx / QQ;
        const int b  = idx - jl * QQ;
        ldsJ[(jl * QQ + b) * APAD + a] = src[idx];
      }
    }
    __syncthreads();
    // Accumulate: one contiguous 21-float LDS row per (n, j).
    for (int jl = 0; jl < tj; ++jl) {
      const int j = j0 + jl;
      const int b = useT ? tokT[j * MM + n] : Xtok[n * LL + j];
      const float* row = &ldsJ[(jl * QQ + b) * APAD];
      const float4* r4 = (const float4*)row;   // 96B-aligned -> b128 OK
      const float4 q0 = r4[0], q1 = r4[1], q2 = r4[2], q3 = r4[3], q4 = r4[4];
      const float q5 = row[20];
      lg[0]  += q0.x; lg[1]  += q0.y; lg[2]  += q0.z; lg[3]  += q0.w;
      lg[4]  += q1.x; lg[5]  += q1.y; lg[6]  += q1.z; lg[7]  += q1.w;
      lg[8]  += q2.x; lg[9]  += q2.y; lg[10] += q2.z; lg[11] += q2.w;
      lg[12] += q3.x; lg[13] += q3.y; lg[14] += q3.z; lg[15] += q3.w;
      lg[16] += q4.x; lg[17] += q4.y; lg[18] += q4.z; lg[19] += q4.w;
      lg[20] += q5;
    }
  }

  // logsumexp over the 21 states
  const float* hi = h + i * QQ;
  float mx = -3.0e38f;
  #pragma unroll
  for (int a = 0; a < QQ; ++a) { lg[a] += hi[a]; mx = fmaxf(mx, lg[a]); }
  float s = 0.0f;
  #pragma unroll
  for (int a = 0; a < QQ; ++a) s += expf(lg[a] - mx);
  const float contrib = w[n] * (mx + logf(s));
  const float tot = block_reduce_sum(contrib);
  if (t == 0) atomicAdd(acc + 2, tot);
}

// ---------------------------------------------------------------------------
// Kernel C: h-side terms + weight normalization + final combine.
// Single block of 256 threads.
// ---------------------------------------------------------------------------
__global__ __launch_bounds__(256) void kern_final(
    const float* __restrict__ h, const float* __restrict__ fi,
    const float* __restrict__ w, const float* __restrict__ acc,
    float* __restrict__ out) {
  const int t = threadIdx.x;
  float hs = 0.0f, eh = 0.0f, ws = 0.0f;
  for (int idx = t; idx < LL * QQ; idx += 256) {
    const float hv = h[idx];
    hs += hv * hv;
    if (idx >= START * QQ) eh += fi[idx] * hv;   // i >= START
  }
  for (int idx = t; idx < MM; idx += 256) ws += w[idx];
  const float ths = block_reduce_sum(hs);
  const float teh = block_reduce_sum(eh);
  const float tws = block_reduce_sum(ws);
  if (t == 0) {
    const float energy = teh + acc[1];
    const float nll = acc[2] / tws - energy;     // -(energy - wlogZ)
    out[0] = nll + RGH * ths + RGJ * acc[0];     // loss
    out[1] = nll;                                // nll
  }
}

extern "C" void kernel_launch(void* const* d_in, const int* in_sizes, int n_in,
                              void* d_out, int out_size, void* d_ws, size_t ws_size,
                              hipStream_t stream) {
  const int*   Xtok = (const int*)  d_in[0];
  const float* wts  = (const float*)d_in[1];
  const float* fi   = (const float*)d_in[2];
  const float* fij  = (const float*)d_in[3];
  const float* h    = (const float*)d_in[4];
  const float* J    = (const float*)d_in[5];
  float* out  = (float*)d_out;
  float* acc  = (float*)d_ws;
  int*   tokT = (int*)((char*)d_ws + 256);
  const size_t need = 256 + (size_t)LL * MM * sizeof(int);
  const int useT = (ws_size >= need) ? 1 : 0;

  hipMemsetAsync(d_ws, 0, 256, stream);  // zero the 3 accumulators
  if (useT) {
    kern_tokT<<<(LL * MM + 255) / 256, 256, 0, stream>>>(Xtok, tokT);
  }
  kern_jsum<<<dim3(LL, 4), 256, 0, stream>>>(J, fij, acc);
  kern_logz<<<dim3(NS, MM / 256), 256, 0, stream>>>(J, Xtok, tokT, useT, h, wts, acc);
  kern_final<<<1, 256, 0, stream>>>(h, fi, wts, acc, out);
}

// Round 2
// 253.841 us; speedup vs baseline: 1.2785x; 1.2785x over previous
//
#include <hip/hip_runtime.h>
#include <cstdint>

// Problem constants (from the reference)
#define LL    200
#define QQ    21
#define MM    1024
#define START 133        // 2*L//3
#define NS    67         // L - START
#define RGH   0.01f
#define RGJ   0.01f

// ws layout (two-phase path):
//   [0,256)                       : acc[0]=sum(J^2), acc[1]=sum(J*fij), acc[2]=sum w*logZ
//   [256, 256+NS*QQ*MM*4)         : logits slab, layout [iIdx][a][n]
//   [.., +LL*MM*4)                : tokT (transposed tokens, [j][n])

#define LOGITS_OFF 256
#define LOGITS_BYTES ((size_t)NS * QQ * MM * 4)          // 5,763,072
#define TOKT_OFF (LOGITS_OFF + LOGITS_BYTES)
#define WS_NEED (TOKT_OFF + (size_t)LL * MM * 4)         // 6,582,528

// LDS row swizzle: row r (= jl*QQ + b) lives at float-offset r*24 + (r%8)*4.
// - offset is a multiple of 4 floats -> 16B-aligned -> ds_read_b128 legal
// - start banks cycle through 8 distinct 4-aligned positions (24*4==96==0 mod 32
//   made plain stride-24 alias every 4 rows; the +4*(r%8) fixes that)
__device__ __forceinline__ int row_off(int r) { return r * 24 + ((r & 7) << 2); }
#define LDSJ_FLOATS 16160   // max row_off(671)+21 = 16153, padded; 64640 B

__device__ __forceinline__ float block_reduce_sum(float v) {
  // blockDim.x == 256 (4 waves) assumed
  __shared__ float sm[4];
  #pragma unroll
  for (int off = 32; off > 0; off >>= 1) v += __shfl_down(v, off, 64);
  const int lane = threadIdx.x & 63;
  const int wv   = threadIdx.x >> 6;
  __syncthreads();
  if (lane == 0) sm[wv] = v;
  __syncthreads();
  float r = 0.0f;
  if (threadIdx.x == 0) r = sm[0] + sm[1] + sm[2] + sm[3];
  return r;  // valid in thread 0 only
}

// ---------------------------------------------------------------------------
// Kernel A: sum(J^2) over all of J, and sum(J*fij) over {i>=START, j<i}.
// float4 everywhere; the j<i mask per (i,a) row is the contiguous prefix
// pos < i*QQ of the 4200-float row, so only the straddling float4 needs
// scalar handling (at most one per row).
// ---------------------------------------------------------------------------
__global__ __launch_bounds__(256) void kern_jsum(
    const float* __restrict__ J, const float* __restrict__ fij,
    float* __restrict__ acc) {
  const int i = blockIdx.x;
  const size_t base4 = (size_t)i * (QQ * LL * QQ / 4);  // 22050 float4 / slice
  const float4* __restrict__ J4 = (const float4*)J + base4;
  const float4* __restrict__ F4 = (const float4*)fij + base4;
  const int total4 = QQ * LL * QQ / 4;  // 22050
  const int lim = i * QQ;               // elems with pos<lim have j<i
  const bool act = (i >= START);
  float j2 = 0.0f, e = 0.0f;
  for (int f = blockIdx.y * 256 + threadIdx.x; f < total4;
       f += 256 * gridDim.y) {
    const float4 v = J4[f];
    j2 += v.x * v.x + v.y * v.y + v.z * v.z + v.w * v.w;
    if (act) {
      const int a   = f / 1050;            // 1050 float4 per 4200-float row
      const int pos = (f - a * 1050) * 4;  // position within the row
      if (pos + 3 < lim) {
        const float4 u = F4[f];
        e += v.x * u.x + v.y * u.y + v.z * u.z + v.w * u.w;
      } else if (pos < lim) {
        const float* vf = (const float*)&v;
        const float* uf = (const float*)(F4 + f);
        for (int k = 0; k < 4 && pos + k < lim; ++k) e += vf[k] * uf[k];
      }
    }
  }
  const float tj2 = block_reduce_sum(j2);
  const float te  = block_reduce_sum(e);
  if (threadIdx.x == 0) {
    atomicAdd(acc + 0, tj2);
    if (act) atomicAdd(acc + 1, te);
  }
}

// ---------------------------------------------------------------------------
// Token transpose: tokT[j][n] = X[n][j]
// ---------------------------------------------------------------------------
__global__ __launch_bounds__(256) void kern_tokT(
    const int* __restrict__ X, int* __restrict__ tokT) {
  const int idx = blockIdx.x * 256 + threadIdx.x;
  if (idx < LL * MM) {
    const int j = idx / MM;
    const int n = idx - j * MM;
    tokT[idx] = X[n * LL + j];
  }
}

// ---------------------------------------------------------------------------
// Phase 1: partial logits. Grid (NS, 2, 4): block = (site i, 512-seq chunk,
// 64-wide j-tile). Two 32-row staging rounds per block. Register partial
// logits, then 21 coalesced atomicAdds per thread into logits[iIdx][a][n].
// ---------------------------------------------------------------------------
__global__ __launch_bounds__(512) void kern_logz_p1(
    const float* __restrict__ J, const int* __restrict__ tokT,
    float* __restrict__ logits) {
  __shared__ __align__(16) float ldsJ[LDSJ_FLOATS];  // 64640 B -> 2 blocks/CU
  const int i  = START + blockIdx.x;
  const int j0 = blockIdx.z * 64;
  if (j0 >= i) return;                 // block-uniform, before any barrier
  const int t = threadIdx.x;
  const int n = blockIdx.y * 512 + t;

  float lg[QQ];
  #pragma unroll
  for (int a = 0; a < QQ; ++a) lg[a] = 0.0f;

  const float* Ji = J + (size_t)i * (QQ * LL * QQ);

  #pragma unroll
  for (int s = 0; s < 2; ++s) {
    const int jb = j0 + 32 * s;
    if (jb >= i) break;                // block-uniform
    const int tj  = min(32, i - jb);
    const int cnt = tj * QQ;
    __syncthreads();
    // Stage J[i,:,jb:jb+tj,:] re-laid-out as swizzled [j][b][a] rows.
    for (int a = 0; a < QQ; ++a) {
      const float* src = Ji + a * (LL * QQ) + jb * QQ;
      for (int idx = t; idx < cnt; idx += 512) {
        const int jl = idx / QQ;
        const int b  = idx - jl * QQ;
        ldsJ[row_off(jl * QQ + b) + a] = src[idx];
      }
    }
    __syncthreads();
    for (int jl = 0; jl < tj; ++jl) {
      const int b = tokT[(jb + jl) * MM + n];
      const float* row = &ldsJ[row_off(jl * QQ + b)];
      const float4* r4 = (const float4*)row;
      const float4 q0 = r4[0], q1 = r4[1], q2 = r4[2], q3 = r4[3], q4 = r4[4];
      const float q5 = row[20];
      lg[0]  += q0.x; lg[1]  += q0.y; lg[2]  += q0.z; lg[3]  += q0.w;
      lg[4]  += q1.x; lg[5]  += q1.y; lg[6]  += q1.z; lg[7]  += q1.w;
      lg[8]  += q2.x; lg[9]  += q2.y; lg[10] += q2.z; lg[11] += q2.w;
      lg[12] += q3.x; lg[13] += q3.y; lg[14] += q3.z; lg[15] += q3.w;
      lg[16] += q4.x; lg[17] += q4.y; lg[18] += q4.z; lg[19] += q4.w;
      lg[20] += q5;
    }
  }

  float* dst = logits + (size_t)blockIdx.x * QQ * MM + n;
  #pragma unroll
  for (int a = 0; a < QQ; ++a) atomicAdd(dst + a * MM, lg[a]);
}

// ---------------------------------------------------------------------------
// Phase 2: logsumexp over a, weighted sum over (n, i). Grid (NS, 4) x 256.
// ---------------------------------------------------------------------------
__global__ __launch_bounds__(256) void kern_logz_p2(
    const float* __restrict__ logits, const float* __restrict__ h,
    const float* __restrict__ w, float* __restrict__ acc) {
  const int iI = blockIdx.x;
  const int i  = START + iI;
  const int t  = threadIdx.x;
  const int n  = blockIdx.y * 256 + t;
  const float* hi = h + i * QQ;
  const float* src = logits + (size_t)iI * QQ * MM + n;
  float lg[QQ];
  float mx = -3.0e38f;
  #pragma unroll
  for (int a = 0; a < QQ; ++a) {
    lg[a] = src[a * MM] + hi[a];
    mx = fmaxf(mx, lg[a]);
  }
  float s = 0.0f;
  #pragma unroll
  for (int a = 0; a < QQ; ++a) s += expf(lg[a] - mx);
  const float contrib = w[n] * (mx + logf(s));
  const float tot = block_reduce_sum(contrib);
  if (t == 0) atomicAdd(acc + 2, tot);
}

// ---------------------------------------------------------------------------
// Fallback monolithic logz (used only if ws is too small for the slab).
// ---------------------------------------------------------------------------
__global__ __launch_bounds__(256) void kern_logz_mono(
    const float* __restrict__ J, const int* __restrict__ Xtok,
    const float* __restrict__ h, const float* __restrict__ w,
    float* __restrict__ acc) {
  __shared__ __align__(16) float ldsJ[LDSJ_FLOATS];
  const int i = START + blockIdx.x;
  const int t = threadIdx.x;
  const int n = blockIdx.y * 256 + t;
  float lg[QQ];
  #pragma unroll
  for (int a = 0; a < QQ; ++a) lg[a] = 0.0f;
  const float* Ji = J + (size_t)i * (QQ * LL * QQ);
  for (int j0 = 0; j0 < i; j0 += 32) {
    const int tj  = min(32, i - j0);
    const int cnt = tj * QQ;
    __syncthreads();
    for (int a = 0; a < QQ; ++a) {
      const float* src = Ji + a * (LL * QQ) + j0 * QQ;
      for (int idx = t; idx < cnt; idx += 256) {
        const int jl = idx / QQ;
        const int b  = idx - jl * QQ;
        ldsJ[row_off(jl * QQ + b) + a] = src[idx];
      }
    }
    __syncthreads();
    for (int jl = 0; jl < tj; ++jl) {
      const int b = Xtok[n * LL + (j0 + jl)];
      const float* row = &ldsJ[row_off(jl * QQ + b)];
      #pragma unroll
      for (int a = 0; a < QQ; ++a) lg[a] += row[a];
    }
  }
  const float* hi = h + i * QQ;
  float mx = -3.0e38f;
  #pragma unroll
  for (int a = 0; a < QQ; ++a) { lg[a] += hi[a]; mx = fmaxf(mx, lg[a]); }
  float s = 0.0f;
  #pragma unroll
  for (int a = 0; a < QQ; ++a) s += expf(lg[a] - mx);
  const float contrib = w[n] * (mx + logf(s));
  const float tot = block_reduce_sum(contrib);
  if (t == 0) atomicAdd(acc + 2, tot);
}

// ---------------------------------------------------------------------------
// Final combine: h-side terms + weight normalization.
// ---------------------------------------------------------------------------
__global__ __launch_bounds__(256) void kern_final(
    const float* __restrict__ h, const float* __restrict__ fi,
    const float* __restrict__ w, const float* __restrict__ acc,
    float* __restrict__ out) {
  const int t = threadIdx.x;
  float hs = 0.0f, eh = 0.0f, ws = 0.0f;
  for (int idx = t; idx < LL * QQ; idx += 256) {
    const float hv = h[idx];
    hs += hv * hv;
    if (idx >= START * QQ) eh += fi[idx] * hv;
  }
  for (int idx = t; idx < MM; idx += 256) ws += w[idx];
  const float ths = block_reduce_sum(hs);
  const float teh = block_reduce_sum(eh);
  const float tws = block_reduce_sum(ws);
  if (t == 0) {
    const float energy = teh + acc[1];
    const float nll = acc[2] / tws - energy;
    out[0] = nll + RGH * ths + RGJ * acc[0];
    out[1] = nll;
  }
}

extern "C" void kernel_launch(void* const* d_in, const int* in_sizes, int n_in,
                              void* d_out, int out_size, void* d_ws, size_t ws_size,
                              hipStream_t stream) {
  const int*   Xtok = (const int*)  d_in[0];
  const float* wts  = (const float*)d_in[1];
  const float* fi   = (const float*)d_in[2];
  const float* fij  = (const float*)d_in[3];
  const float* h    = (const float*)d_in[4];
  const float* J    = (const float*)d_in[5];
  float* out    = (float*)d_out;
  float* acc    = (float*)d_ws;
  float* logits = (float*)((char*)d_ws + LOGITS_OFF);
  int*   tokT   = (int*)  ((char*)d_ws + TOKT_OFF);

  if (ws_size >= WS_NEED) {
    // zero acc + logits slab in one memset
    hipMemsetAsync(d_ws, 0, TOKT_OFF, stream);
    kern_tokT<<<(LL * MM + 255) / 256, 256, 0, stream>>>(Xtok, tokT);
    kern_jsum<<<dim3(LL, 4), 256, 0, stream>>>(J, fij, acc);
    kern_logz_p1<<<dim3(NS, 2, 4), 512, 0, stream>>>(J, tokT, logits);
    kern_logz_p2<<<dim3(NS, 4), 256, 0, stream>>>(logits, h, wts, acc);
    kern_final<<<1, 256, 0, stream>>>(h, fi, wts, acc, out);
  } else {
    hipMemsetAsync(d_ws, 0, 256, stream);
    kern_jsum<<<dim3(LL, 4), 256, 0, stream>>>(J, fij, acc);
    kern_logz_mono<<<dim3(NS, 4), 256, 0, stream>>>(J, Xtok, h, wts, acc);
    kern_final<<<1, 256, 0, stream>>>(h, fi, wts, acc, out);
  }
}